// Round 4
// baseline (206.867 us; speedup 1.0000x reference)
//
#include <hip/hip_runtime.h>
#include <hip/hip_bf16.h>

// GCLSTM with H=C=None collapses to: gates from x@Wx only (conv = bconv const),
// forget gate dead, graph unused.
//   h1 = sig(zo)*tanh(sig(zi)*tanh(zc)),  z = x@Wx1[:,{i,c,o}] + bias
//   h2 = same with Wx2; out = relu(h2)@Wl + bl
//
// R4 vs R3 (R3: ~35us, 1 wave/SIMD, 224 VGPRs of B frags, 2 LDS round trips):
//  - B1 fragments in LDS (staged once/block), B2 hi+lo stays in VGPRs.
//  - B1 columns permuted at pack time so a channel's 3 gates land in the SAME
//    lane of MFMA C-layout (col = c%16 + 16*(3*(c/16)+g)); gates computed from
//    acc registers directly -> z1 LDS round trip eliminated. Channels 48,49
//    ride tile t=9 via a tiny per-wave LDS spill. Biases folded into acc init.
//  - __launch_bounds__(256,2): 2 waves/SIMD (VGPR ~210), 512 blocks resident.
//  - hw packed cvt (v_cvt_pk_bf16_f32) for fp32->bf16 hi/lo splits.

#define NODES 100000
#define NTILES 6250
#define GRID_BLOCKS 512
#define WAVES_TOTAL 2048

typedef float v4f   __attribute__((ext_vector_type(4)));
typedef float fragC __attribute__((ext_vector_type(4)));
typedef short frag8 __attribute__((ext_vector_type(8)));

// ws byte offsets
#define OFF_B1H 0       // 10 tiles * 4 s * 1024 B = 40960
#define OFF_B2H 40960   // 8 frags * 1024 B
#define OFF_B2L 49152   // 8 frags * 1024 B
#define OFF_PB1 57344   // 160 f32, packed-col order
#define OFF_PB2 57984   // 64 f32, packed-col order

__device__ __forceinline__ unsigned short f2bf(float f) {
  unsigned int u = __float_as_uint(f);
  u += 0x7fffu + ((u >> 16) & 1u);  // RNE
  return (unsigned short)(u >> 16);
}
__device__ __forceinline__ float bf2f(unsigned short h) {
  return __uint_as_float(((unsigned int)h) << 16);
}
__device__ __forceinline__ float fsig(float z) {
  float t = __builtin_amdgcn_exp2f(z * -1.44269504088896f);
  return __builtin_amdgcn_rcpf(1.0f + t);
}
__device__ __forceinline__ float ftanh(float z) {
  float t = __builtin_amdgcn_exp2f(z * 2.88539008177793f);
  return 1.0f - 2.0f * __builtin_amdgcn_rcpf(t + 1.0f);
}

union bfu { __hip_bfloat162 h; unsigned int u; };

__device__ __forceinline__ void cvt8(const float* v, frag8& hi, frag8& lo) {
  float lof[8];
#pragma unroll
  for (int p = 0; p < 4; ++p) {
    bfu c; c.h = __float22bfloat162_rn(make_float2(v[2 * p], v[2 * p + 1]));
    hi[2 * p]     = (short)(c.u & 0xffffu);
    hi[2 * p + 1] = (short)(c.u >> 16);
    lof[2 * p]     = v[2 * p]     - __uint_as_float((c.u & 0xffffu) << 16);
    lof[2 * p + 1] = v[2 * p + 1] - __uint_as_float(c.u & 0xffff0000u);
  }
#pragma unroll
  for (int p = 0; p < 4; ++p) {
    bfu c; c.h = __float22bfloat162_rn(make_float2(lof[2 * p], lof[2 * p + 1]));
    lo[2 * p]     = (short)(c.u & 0xffffu);
    lo[2 * p + 1] = (short)(c.u >> 16);
  }
}

// B1 packed-col mapping: col = 16t+m.  t<=8: b=t/3,g=t%3,c=16b+m.
// t==9: m<6 -> c=48+m/3, g=m%3; else zero-pad.  g in {i,c,o} -> Wx1 col {0,2,3}.
__global__ void pack_weights(const float* __restrict__ Wx1, const float* __restrict__ bx1,
                             const float* __restrict__ bconv1,
                             const float* __restrict__ Wx2, const float* __restrict__ bx2,
                             const float* __restrict__ bconv2,
                             unsigned char* __restrict__ ws) {
  const int tid = blockIdx.x * blockDim.x + threadIdx.x;
  const int stride = gridDim.x * blockDim.x;
  unsigned short* B1H = (unsigned short*)(ws + OFF_B1H);
  unsigned short* B2H = (unsigned short*)(ws + OFF_B2H);
  unsigned short* B2L = (unsigned short*)(ws + OFF_B2L);
  float* PB1 = (float*)(ws + OFF_PB1);
  float* PB2 = (float*)(ws + OFF_PB2);

  for (int idx = tid; idx < 20480; idx += stride) {
    int j = idx & 7, lane = (idx >> 3) & 63, ft = idx >> 9;  // ft = s*10+t
    int s = ft / 10, t = ft % 10;
    int k = 32 * s + ((lane >> 4) << 3) + j;
    int m = lane & 15;
    int c = -1, g = 0;
    if (t <= 8) { g = t % 3; c = 16 * (t / 3) + m; }
    else if (m < 6) { c = 48 + m / 3; g = m % 3; }
    float val = 0.f;
    if (c >= 0) {
      int gs = (g == 0) ? 0 : (g == 1) ? 2 : 3;
      val = Wx1[k * 200 + gs * 50 + c];
    }
    B1H[idx] = f2bf(val);
  }
  // B2: [64 x 64] zero-padded from [50 x 60], plain col = g*20+cc
  for (int idx = tid; idx < 4096; idx += stride) {
    int j = idx & 7, lane = (idx >> 3) & 63, ft = idx >> 9;  // ft = s*4+t
    int s = ft >> 2, t = ft & 3;
    int k = 32 * s + ((lane >> 4) << 3) + j;
    int n = 16 * t + (lane & 15);
    float val = 0.f;
    if (k < 50 && n < 60) {
      int g = n / 20, cc = n % 20;
      int gs = (g == 0) ? 0 : (g == 1) ? 2 : 3;
      val = Wx2[k * 80 + gs * 20 + cc];
    }
    unsigned short h = f2bf(val);
    B2H[idx] = h;
    B2L[idx] = f2bf(val - bf2f(h));
  }
  for (int idx = tid; idx < 160; idx += stride) {
    int t = idx >> 4, m = idx & 15;
    int c = -1, g = 0;
    if (t <= 8) { g = t % 3; c = 16 * (t / 3) + m; }
    else if (m < 6) { c = 48 + m / 3; g = m % 3; }
    float v = 0.f;
    if (c >= 0) {
      int gs = (g == 0) ? 0 : (g == 1) ? 2 : 3;
      v = bx1[gs * 50 + c] + bconv1[gs * 50 + c];
    }
    PB1[idx] = v;
  }
  for (int idx = tid; idx < 64; idx += stride) {
    float v = 0.f;
    if (idx < 60) {
      int g = idx / 20, cc = idx % 20;
      int gs = (g == 0) ? 0 : (g == 1) ? 2 : 3;
      v = bx2[gs * 20 + cc] + bconv2[gs * 20 + cc];
    }
    PB2[idx] = v;
  }
}

__global__ __launch_bounds__(256, 2) void gclstm_main(
    const float* __restrict__ x, const unsigned char* __restrict__ wsb,
    const float* __restrict__ Wl, const float* __restrict__ bl,
    float* __restrict__ out) {
  __shared__ short sB1[20480];       // 40960 B, B1 fragments
  __shared__ float sH[4][16 * 68];   // per-wave h1 / z2 scratch (pitch 68)
  __shared__ float sT9[4][16 * 6];   // per-wave t=9 spill (channels 48,49)

  const int tid = threadIdx.x;
  const int lane = tid & 63;
  const int wave = tid >> 6;
  const int m = lane & 15;
  const int q = lane >> 4;

  {  // stage B1 -> LDS once
    const v4f* g = (const v4f*)(wsb + OFF_B1H);
    v4f* s = (v4f*)sB1;
    for (int i = tid; i < 2560; i += 256) s[i] = g[i];
  }
  __syncthreads();

  frag8 b2h[8], b2l[8];
  {
    const frag8* g2h = (const frag8*)(wsb + OFF_B2H);
    const frag8* g2l = (const frag8*)(wsb + OFF_B2L);
#pragma unroll
    for (int i = 0; i < 8; ++i) {
      b2h[i] = g2h[i * 64 + lane];
      b2l[i] = g2l[i * 64 + lane];
    }
  }
  float bias1v[10], bias2v[4], wlv[5];
  {
    const float* pb1 = (const float*)(wsb + OFF_PB1);
    const float* pb2 = (const float*)(wsb + OFF_PB2);
#pragma unroll
    for (int t = 0; t < 10; ++t) bias1v[t] = pb1[16 * t + m];
#pragma unroll
    for (int t = 0; t < 4; ++t) bias2v[t] = pb2[16 * t + m];
#pragma unroll
    for (int it = 0; it < 5; ++it) wlv[it] = Wl[q + 4 * it];
  }
  const float blv = bl[0];

  float* sHw = (float*)sH + wave * (16 * 68);
  float* sT9w = (float*)sT9 + wave * (16 * 6);
  const frag8* sB1f = (const frag8*)sB1;
  const int gw = blockIdx.x * 4 + wave;

  v4f abuf[8];
  int tau = gw;
  if (tau < NTILES) {
    const float* xr = x + (size_t)(tau * 16 + m) * 128 + q * 8;
#pragma unroll
    for (int s = 0; s < 4; ++s) {
      abuf[2 * s] = *(const v4f*)(xr + 32 * s);
      abuf[2 * s + 1] = *(const v4f*)(xr + 32 * s + 4);
    }
  }

  for (; tau < NTILES; tau += WAVES_TOTAL) {
    frag8 ah[4], al[4];
#pragma unroll
    for (int s = 0; s < 4; ++s) {
      float av[8];
      *(v4f*)av = abuf[2 * s];
      *(v4f*)(av + 4) = abuf[2 * s + 1];
      cvt8(av, ah[s], al[s]);
    }
    int tn = tau + WAVES_TOTAL;
    if (tn < NTILES) {  // prefetch next tile's x
      const float* xr = x + (size_t)(tn * 16 + m) * 128 + q * 8;
#pragma unroll
      for (int s = 0; s < 4; ++s) {
        abuf[2 * s] = *(const v4f*)(xr + 32 * s);
        abuf[2 * s + 1] = *(const v4f*)(xr + 32 * s + 4);
      }
    }

    // ---- GEMM1: z1[16 x 160] = A(hi+lo) @ B1h, bias in acc init ----
    fragC acc[10];
#pragma unroll
    for (int t = 0; t < 10; ++t)
      acc[t] = (fragC){bias1v[t], bias1v[t], bias1v[t], bias1v[t]};
#pragma unroll
    for (int s = 0; s < 4; ++s)
#pragma unroll
      for (int t = 0; t < 10; ++t) {
        frag8 b = sB1f[(s * 10 + t) * 64 + lane];
        acc[t] = __builtin_amdgcn_mfma_f32_16x16x32_bf16(ah[s], b, acc[t], 0, 0, 0);
        acc[t] = __builtin_amdgcn_mfma_f32_16x16x32_bf16(al[s], b, acc[t], 0, 0, 0);
      }

    // gates straight from registers: lane (m,q) holds rows q*4+r, channel 16b+m
#pragma unroll
    for (int b = 0; b < 3; ++b)
#pragma unroll
      for (int r = 0; r < 4; ++r) {
        float I = fsig(acc[3 * b][r]);
        float T = ftanh(acc[3 * b + 1][r]);
        float O = fsig(acc[3 * b + 2][r]);
        sHw[(q * 4 + r) * 68 + 16 * b + m] = O * ftanh(I * T);
      }
    if (m >= 2) {  // K-pad cols 50..63 for GEMM2
#pragma unroll
      for (int r = 0; r < 4; ++r) sHw[(q * 4 + r) * 68 + 48 + m] = 0.f;
    }
    if (m < 6) {  // t=9 spill: channels 48,49 gate triples
#pragma unroll
      for (int r = 0; r < 4; ++r) sT9w[(q * 4 + r) * 6 + m] = acc[9][r];
    }
    if (lane < 32) {  // finish channels 48,49 (same-wave DS ordering)
      int row = lane & 15, cc = lane >> 4;
      float I = fsig(sT9w[row * 6 + 3 * cc]);
      float T = ftanh(sT9w[row * 6 + 3 * cc + 1]);
      float O = fsig(sT9w[row * 6 + 3 * cc + 2]);
      sHw[row * 68 + 48 + cc] = O * ftanh(I * T);
    }

    // ---- GEMM2: z2[16 x 64] = h1(hi+lo) @ B2(hi+lo), K padded to 64 ----
    frag8 hh[2], hl[2];
#pragma unroll
    for (int s = 0; s < 2; ++s) {
      float hv[8];
      *(v4f*)hv = *(const v4f*)(sHw + m * 68 + 32 * s + q * 8);
      *(v4f*)(hv + 4) = *(const v4f*)(sHw + m * 68 + 32 * s + q * 8 + 4);
      cvt8(hv, hh[s], hl[s]);
    }
    fragC acc2[4];
#pragma unroll
    for (int t = 0; t < 4; ++t)
      acc2[t] = (fragC){bias2v[t], bias2v[t], bias2v[t], bias2v[t]};
#pragma unroll
    for (int s = 0; s < 2; ++s)
#pragma unroll
      for (int t = 0; t < 4; ++t) {
        acc2[t] = __builtin_amdgcn_mfma_f32_16x16x32_bf16(hh[s], b2h[s * 4 + t], acc2[t], 0, 0, 0);
        acc2[t] = __builtin_amdgcn_mfma_f32_16x16x32_bf16(hl[s], b2h[s * 4 + t], acc2[t], 0, 0, 0);
        acc2[t] = __builtin_amdgcn_mfma_f32_16x16x32_bf16(hh[s], b2l[s * 4 + t], acc2[t], 0, 0, 0);
      }
#pragma unroll
    for (int t = 0; t < 4; ++t)
#pragma unroll
      for (int r = 0; r < 4; ++r)
        sHw[(q * 4 + r) * 68 + 16 * t + m] = acc2[t][r];

    // epilogue: node=m, channels jj=q+4it; reduce over q via shfl
    float part = 0.f;
#pragma unroll
    for (int it = 0; it < 5; ++it) {
      int jj = q + 4 * it;
      float I = fsig(sHw[m * 68 + jj]);
      float T = ftanh(sHw[m * 68 + 20 + jj]);
      float O = fsig(sHw[m * 68 + 40 + jj]);
      float h2 = O * ftanh(I * T);
      part += fmaxf(h2, 0.f) * wlv[it];
    }
    part += __shfl_xor(part, 16);
    part += __shfl_xor(part, 32);
    if (q == 0) out[tau * 16 + m] = part + blv;
  }
}

extern "C" void kernel_launch(void* const* d_in, const int* in_sizes, int n_in,
                              void* d_out, int out_size, void* d_ws, size_t ws_size,
                              hipStream_t stream) {
  (void)in_sizes; (void)n_in; (void)out_size; (void)ws_size;
  const float* x = (const float*)d_in[0];
  // d_in[1] edge_index, d_in[2] edge_weight, d_in[5] theta1, d_in[9] theta2: dead
  const float* Wx1 = (const float*)d_in[3];
  const float* bx1 = (const float*)d_in[4];
  const float* bconv1 = (const float*)d_in[6];
  const float* Wx2 = (const float*)d_in[7];
  const float* bx2 = (const float*)d_in[8];
  const float* bconv2 = (const float*)d_in[10];
  const float* Wl = (const float*)d_in[11];
  const float* bl = (const float*)d_in[12];
  unsigned char* ws = (unsigned char*)d_ws;  // needs ~58.3 KB

  hipLaunchKernelGGL(pack_weights, dim3(32), dim3(256), 0, stream,
                     Wx1, bx1, bconv1, Wx2, bx2, bconv2, ws);
  hipLaunchKernelGGL(gclstm_main, dim3(GRID_BLOCKS), dim3(256), 0, stream,
                     x, ws, Wl, bl, (float*)d_out);
}

// Round 5
// 192.535 us; speedup vs baseline: 1.0744x; 1.0744x over previous
//
#include <hip/hip_runtime.h>
#include <hip/hip_bf16.h>

// GCLSTM with H=C=None collapses to: gates from x@Wx only (conv = bconv const),
// forget gate dead, graph unused.
//   h1 = sig(zo)*tanh(sig(zi)*tanh(zc)),  z = x@Wx1[:,{i,c,o}] + bias
//   h2 = same with Wx2; out = relu(h2)@Wl + bl
//
// R5 vs R4 (R4 spilled ~60 regs: 114 MB scratch writes, main 103us):
//  - fit the (256,2) budget for real: B2 hi-only in VGPRs (32), h1 stored as
//    bf16 directly in LDS (no fp32 h + re-cvt), B1 frags in LDS as before.
//  - B2 packed-col too: channel's 3 gates on one lane of C-layout; epilogue
//    entirely in registers + shfl (no GEMM2 LDS round trip). GEMM1 ch48/49
//    finished via shfl (no spill buffer).
//  - LDS 50.2 KB; K-pad cols of h zeroed once pre-loop.

#define NODES 100000
#define NTILES 6250
#define GRID_BLOCKS 512
#define WAVES_TOTAL 2048

typedef float v4f   __attribute__((ext_vector_type(4)));
typedef float fragC __attribute__((ext_vector_type(4)));
typedef short frag8 __attribute__((ext_vector_type(8)));

// ws byte offsets
#define OFF_B1H 0       // 40 frags * 1024 B
#define OFF_B2H 40960   // 8 frags * 1024 B
#define OFF_PB1 49152   // 160 f32 packed-col biases (layer1)
#define OFF_PB2 49792   // 64 f32 packed-col biases (layer2)

__device__ __forceinline__ unsigned short f2bf(float f) {
  unsigned int u = __float_as_uint(f);
  u += 0x7fffu + ((u >> 16) & 1u);  // RNE
  return (unsigned short)(u >> 16);
}
__device__ __forceinline__ float fsig(float z) {
  float t = __builtin_amdgcn_exp2f(z * -1.44269504088896f);
  return __builtin_amdgcn_rcpf(1.0f + t);
}
__device__ __forceinline__ float ftanh(float z) {
  float t = __builtin_amdgcn_exp2f(z * 2.88539008177793f);
  return 1.0f - 2.0f * __builtin_amdgcn_rcpf(t + 1.0f);
}

union bfu { __hip_bfloat162 h; unsigned int u; };

__device__ __forceinline__ void cvt8(const float* v, frag8& hi, frag8& lo) {
  float lof[8];
#pragma unroll
  for (int p = 0; p < 4; ++p) {
    bfu c; c.h = __float22bfloat162_rn(make_float2(v[2 * p], v[2 * p + 1]));
    hi[2 * p]     = (short)(c.u & 0xffffu);
    hi[2 * p + 1] = (short)(c.u >> 16);
    lof[2 * p]     = v[2 * p]     - __uint_as_float((c.u & 0xffffu) << 16);
    lof[2 * p + 1] = v[2 * p + 1] - __uint_as_float(c.u & 0xffff0000u);
  }
#pragma unroll
  for (int p = 0; p < 4; ++p) {
    bfu c; c.h = __float22bfloat162_rn(make_float2(lof[2 * p], lof[2 * p + 1]));
    lo[2 * p]     = (short)(c.u & 0xffffu);
    lo[2 * p + 1] = (short)(c.u >> 16);
  }
}

// B1 packed-col: col = 16t+m.  t<=8: g=t%3, c=16*(t/3)+m.
// t==9: m<6 -> c=48+m/3, g=m%3; else pad.  g {i,c,o} -> Wx1 col {0,2,3}.
// B2 packed-col: col = 16t+m.  t<=2: g=t, c=m.
// t==3: m<12 -> c=16+m/3, g=m%3; else pad.  g -> Wx2 col {0,2,3}.
__global__ void pack_weights(const float* __restrict__ Wx1, const float* __restrict__ bx1,
                             const float* __restrict__ bconv1,
                             const float* __restrict__ Wx2, const float* __restrict__ bx2,
                             const float* __restrict__ bconv2,
                             unsigned char* __restrict__ ws) {
  const int tid = blockIdx.x * blockDim.x + threadIdx.x;
  const int stride = gridDim.x * blockDim.x;
  unsigned short* B1H = (unsigned short*)(ws + OFF_B1H);
  unsigned short* B2H = (unsigned short*)(ws + OFF_B2H);
  float* PB1 = (float*)(ws + OFF_PB1);
  float* PB2 = (float*)(ws + OFF_PB2);

  for (int idx = tid; idx < 20480; idx += stride) {
    int j = idx & 7, lane = (idx >> 3) & 63, ft = idx >> 9;  // ft = s*10+t
    int s = ft / 10, t = ft % 10;
    int k = 32 * s + ((lane >> 4) << 3) + j;
    int m = lane & 15;
    int c = -1, g = 0;
    if (t <= 8) { g = t % 3; c = 16 * (t / 3) + m; }
    else if (m < 6) { c = 48 + m / 3; g = m % 3; }
    float val = 0.f;
    if (c >= 0) {
      int gs = (g == 0) ? 0 : (g == 1) ? 2 : 3;
      val = Wx1[k * 200 + gs * 50 + c];
    }
    B1H[idx] = f2bf(val);
  }
  for (int idx = tid; idx < 4096; idx += stride) {
    int j = idx & 7, lane = (idx >> 3) & 63, ft = idx >> 9;  // ft = s*4+t
    int s = ft >> 2, t = ft & 3;
    int k = 32 * s + ((lane >> 4) << 3) + j;
    int m = lane & 15;
    int c = -1, g = 0;
    if (t <= 2) { g = t; c = m; }
    else if (m < 12) { c = 16 + m / 3; g = m % 3; }
    float val = 0.f;
    if (c >= 0 && k < 50) {
      int gs = (g == 0) ? 0 : (g == 1) ? 2 : 3;
      val = Wx2[k * 80 + gs * 20 + c];
    }
    B2H[idx] = f2bf(val);
  }
  for (int idx = tid; idx < 160; idx += stride) {
    int t = idx >> 4, m = idx & 15;
    int c = -1, g = 0;
    if (t <= 8) { g = t % 3; c = 16 * (t / 3) + m; }
    else if (m < 6) { c = 48 + m / 3; g = m % 3; }
    float v = 0.f;
    if (c >= 0) {
      int gs = (g == 0) ? 0 : (g == 1) ? 2 : 3;
      v = bx1[gs * 50 + c] + bconv1[gs * 50 + c];
    }
    PB1[idx] = v;
  }
  for (int idx = tid; idx < 64; idx += stride) {
    int t = idx >> 4, m = idx & 15;
    int c = -1, g = 0;
    if (t <= 2) { g = t; c = m; }
    else if (m < 12) { c = 16 + m / 3; g = m % 3; }
    float v = 0.f;
    if (c >= 0) {
      int gs = (g == 0) ? 0 : (g == 1) ? 2 : 3;
      v = bx2[gs * 20 + c] + bconv2[gs * 20 + c];
    }
    PB2[idx] = v;
  }
}

__global__ __launch_bounds__(256, 2) void gclstm_main(
    const float* __restrict__ x, const unsigned char* __restrict__ wsb,
    const float* __restrict__ Wl, const float* __restrict__ bl,
    float* __restrict__ out) {
  __shared__ short sB1[20480];                  // 40960 B: B1 fragments (bf16)
  __shared__ unsigned short sH[4][16 * 72];     // 9216 B: per-wave h1 (bf16, pitch 72)

  const int tid = threadIdx.x;
  const int lane = tid & 63;
  const int wave = tid >> 6;
  const int m = lane & 15;
  const int q = lane >> 4;

  {  // stage B1 -> LDS once; zero h scratch (K-pad cols never written in-loop)
    const v4f* g = (const v4f*)(wsb + OFF_B1H);
    v4f* s = (v4f*)sB1;
    for (int i = tid; i < 2560; i += 256) s[i] = g[i];
    unsigned int* hz = (unsigned int*)sH;
    for (int i = tid; i < 2304; i += 256) hz[i] = 0u;
  }
  __syncthreads();

  frag8 b2h[8];
  {
    const frag8* g2h = (const frag8*)(wsb + OFF_B2H);
#pragma unroll
    for (int i = 0; i < 8; ++i) b2h[i] = g2h[i * 64 + lane];
  }
  float bias1v[10], bias2v[4];
  {
    const float* pb1 = (const float*)(wsb + OFF_PB1);
    const float* pb2 = (const float*)(wsb + OFF_PB2);
#pragma unroll
    for (int t = 0; t < 10; ++t) bias1v[t] = pb1[16 * t + m];
#pragma unroll
    for (int t = 0; t < 4; ++t) bias2v[t] = pb2[16 * t + m];
  }
  const float wlm = Wl[m];
  const float wlx = (m < 4) ? Wl[16 + m] : 0.f;
  const float blv = bl[0];

  unsigned short* sHw = (unsigned short*)sH + wave * (16 * 72);
  const frag8* sB1f = (const frag8*)sB1;
  const int gw = blockIdx.x * 4 + wave;

  v4f abuf[8];
  int tau = gw;
  {
    const float* xr = x + (size_t)(tau * 16 + m) * 128 + q * 8;
#pragma unroll
    for (int s = 0; s < 4; ++s) {
      abuf[2 * s] = *(const v4f*)(xr + 32 * s);
      abuf[2 * s + 1] = *(const v4f*)(xr + 32 * s + 4);
    }
  }

  for (; tau < NTILES; tau += WAVES_TOTAL) {
    frag8 ah[4], al[4];
#pragma unroll
    for (int s = 0; s < 4; ++s) {
      float av[8];
      *(v4f*)av = abuf[2 * s];
      *(v4f*)(av + 4) = abuf[2 * s + 1];
      cvt8(av, ah[s], al[s]);
    }
    int tn = tau + WAVES_TOTAL;
    if (tn < NTILES) {  // prefetch next tile's x
      const float* xr = x + (size_t)(tn * 16 + m) * 128 + q * 8;
#pragma unroll
      for (int s = 0; s < 4; ++s) {
        abuf[2 * s] = *(const v4f*)(xr + 32 * s);
        abuf[2 * s + 1] = *(const v4f*)(xr + 32 * s + 4);
      }
    }

    // ---- GEMM1: z1[16 x 160] = A(hi+lo) @ B1h, bias folded into acc ----
    fragC acc[10];
#pragma unroll
    for (int t = 0; t < 10; ++t)
      acc[t] = (fragC){bias1v[t], bias1v[t], bias1v[t], bias1v[t]};
#pragma unroll
    for (int s = 0; s < 4; ++s)
#pragma unroll
      for (int t = 0; t < 10; ++t) {
        frag8 b = sB1f[(s * 10 + t) * 64 + lane];
        acc[t] = __builtin_amdgcn_mfma_f32_16x16x32_bf16(ah[s], b, acc[t], 0, 0, 0);
        acc[t] = __builtin_amdgcn_mfma_f32_16x16x32_bf16(al[s], b, acc[t], 0, 0, 0);
      }

    // gates from registers (packed-col): lane (m,q) -> rows 4q+r, channel 16b+m
#pragma unroll
    for (int b = 0; b < 3; ++b)
#pragma unroll
      for (int r = 0; r < 4; ++r) {
        float I = fsig(acc[3 * b][r]);
        float T = ftanh(acc[3 * b + 1][r]);
        float O = fsig(acc[3 * b + 2][r]);
        sHw[(q * 4 + r) * 72 + 16 * b + m] = f2bf(O * ftanh(I * T));
      }
    // channels 48,49 from acc[9] via shfl: c48 on lanes 16q+{0,1,2}, c49 on +{3,4,5}
#pragma unroll
    for (int r = 0; r < 4; ++r) {
      float vI = __shfl(acc[9][r], 16 * q + m);
      float vT = __shfl(acc[9][r], 16 * q + m + 1);
      float vO = __shfl(acc[9][r], 16 * q + m + 2);
      if (m == 0 || m == 3) {
        float I = fsig(vI), T = ftanh(vT), O = fsig(vO);
        sHw[(q * 4 + r) * 72 + 48 + (m >> 1)] = f2bf(O * ftanh(I * T));
      }
    }

    // ---- GEMM2: z2[16 x 64] = h1(bf16) @ B2h, K padded to 64 ----
    frag8 hh[2];
#pragma unroll
    for (int s = 0; s < 2; ++s)
      hh[s] = *(const frag8*)(sHw + m * 72 + 32 * s + 8 * q);
    fragC acc2[4];
#pragma unroll
    for (int t = 0; t < 4; ++t)
      acc2[t] = (fragC){bias2v[t], bias2v[t], bias2v[t], bias2v[t]};
#pragma unroll
    for (int s = 0; s < 2; ++s)
#pragma unroll
      for (int t = 0; t < 4; ++t)
        acc2[t] = __builtin_amdgcn_mfma_f32_16x16x32_bf16(hh[s], b2h[s * 4 + t], acc2[t], 0, 0, 0);

    // epilogue in registers: lane owns channel m (t=0,1,2) and (m<4) ch 16+m via shfl
    v4f res;
#pragma unroll
    for (int r = 0; r < 4; ++r) {
      float I = fsig(acc2[0][r]);
      float T = ftanh(acc2[1][r]);
      float O = fsig(acc2[2][r]);
      float h2 = O * ftanh(I * T);
      float part = fmaxf(h2, 0.f) * wlm;
      float eI = __shfl(acc2[3][r], 16 * q + 3 * m);
      float eT = __shfl(acc2[3][r], 16 * q + 3 * m + 1);
      float eO = __shfl(acc2[3][r], 16 * q + 3 * m + 2);
      float I2 = fsig(eI), T2 = ftanh(eT), O2 = fsig(eO);
      float h2x = O2 * ftanh(I2 * T2);
      part += fmaxf(h2x, 0.f) * wlx;
      part += __shfl_xor(part, 1);
      part += __shfl_xor(part, 2);
      part += __shfl_xor(part, 4);
      part += __shfl_xor(part, 8);
      res[r] = part + blv;
    }
    if (m == 0) *(v4f*)(out + tau * 16 + 4 * q) = res;
  }
}

extern "C" void kernel_launch(void* const* d_in, const int* in_sizes, int n_in,
                              void* d_out, int out_size, void* d_ws, size_t ws_size,
                              hipStream_t stream) {
  (void)in_sizes; (void)n_in; (void)out_size; (void)ws_size;
  const float* x = (const float*)d_in[0];
  // d_in[1] edge_index, d_in[2] edge_weight, d_in[5] theta1, d_in[9] theta2: dead
  const float* Wx1 = (const float*)d_in[3];
  const float* bx1 = (const float*)d_in[4];
  const float* bconv1 = (const float*)d_in[6];
  const float* Wx2 = (const float*)d_in[7];
  const float* bx2 = (const float*)d_in[8];
  const float* bconv2 = (const float*)d_in[10];
  const float* Wl = (const float*)d_in[11];
  const float* bl = (const float*)d_in[12];
  unsigned char* ws = (unsigned char*)d_ws;  // needs ~50 KB

  hipLaunchKernelGGL(pack_weights, dim3(32), dim3(256), 0, stream,
                     Wx1, bx1, bconv1, Wx2, bx2, bconv2, ws);
  hipLaunchKernelGGL(gclstm_main, dim3(GRID_BLOCKS), dim3(256), 0, stream,
                     x, ws, Wl, bl, (float*)d_out);
}

// Round 6
// 132.630 us; speedup vs baseline: 1.5597x; 1.4517x over previous
//
#include <hip/hip_runtime.h>
#include <hip/hip_bf16.h>

// GCLSTM with H=C=None collapses to: gates from x@Wx only (conv = bconv const),
// forget gate dead, graph unused.
//   h1 = sig(zo)*tanh(sig(zi)*tanh(zc)),  z = x@Wx1[:,{i,c,o}] + bias
//   h2 = same with Wx2; out = relu(h2)@Wl + bl
//
// R6 vs R5 (R5 still spilled ~62 dwords/lane/iter: WRITE 100MB, main 88us):
//  - b2h AND biases moved to LDS: persistent arch regs ~76 (abuf 32 + ah/al 32
//    + addressing).
//  - sched_barrier(0) between GEMM1's 4 k-stages: scheduler can hoist at most
//    10 B1 frags (40 VGPRs) instead of all 40 (160 VGPRs) -> peak ~125 < 128
//    cap at (256,2); the R4/R5 spill storm came from this hoisting.
//  - numerics identical to R5: A hi/lo split, bf16 h1 in LDS, B2 hi-only,
//    packed-col gates from registers, shfl epilogue.

#define NODES 100000
#define NTILES 6250
#define GRID_BLOCKS 512
#define WAVES_TOTAL 2048

typedef float v4f   __attribute__((ext_vector_type(4)));
typedef float fragC __attribute__((ext_vector_type(4)));
typedef short frag8 __attribute__((ext_vector_type(8)));

// ws byte offsets
#define OFF_B1H 0       // 40 frags * 1024 B
#define OFF_B2H 40960   // 8 frags * 1024 B
#define OFF_PB1 49152   // 160 f32 packed-col biases (layer1)
#define OFF_PB2 49792   // 64 f32 packed-col biases (layer2)

__device__ __forceinline__ unsigned short f2bf(float f) {
  unsigned int u = __float_as_uint(f);
  u += 0x7fffu + ((u >> 16) & 1u);  // RNE
  return (unsigned short)(u >> 16);
}
__device__ __forceinline__ float fsig(float z) {
  float t = __builtin_amdgcn_exp2f(z * -1.44269504088896f);
  return __builtin_amdgcn_rcpf(1.0f + t);
}
__device__ __forceinline__ float ftanh(float z) {
  float t = __builtin_amdgcn_exp2f(z * 2.88539008177793f);
  return 1.0f - 2.0f * __builtin_amdgcn_rcpf(t + 1.0f);
}

union bfu { __hip_bfloat162 h; unsigned int u; };

__device__ __forceinline__ void cvt8(const float* v, frag8& hi, frag8& lo) {
  float lof[8];
#pragma unroll
  for (int p = 0; p < 4; ++p) {
    bfu c; c.h = __float22bfloat162_rn(make_float2(v[2 * p], v[2 * p + 1]));
    hi[2 * p]     = (short)(c.u & 0xffffu);
    hi[2 * p + 1] = (short)(c.u >> 16);
    lof[2 * p]     = v[2 * p]     - __uint_as_float((c.u & 0xffffu) << 16);
    lof[2 * p + 1] = v[2 * p + 1] - __uint_as_float(c.u & 0xffff0000u);
  }
#pragma unroll
  for (int p = 0; p < 4; ++p) {
    bfu c; c.h = __float22bfloat162_rn(make_float2(lof[2 * p], lof[2 * p + 1]));
    lo[2 * p]     = (short)(c.u & 0xffffu);
    lo[2 * p + 1] = (short)(c.u >> 16);
  }
}

// B1 packed-col: col = 16t+m.  t<=8: g=t%3, c=16*(t/3)+m.
// t==9: m<6 -> c=48+m/3, g=m%3; else pad.  g {i,c,o} -> Wx1 col {0,2,3}.
// B2 packed-col: col = 16t+m.  t<=2: g=t, c=m.
// t==3: m<12 -> c=16+m/3, g=m%3; else pad.  g -> Wx2 col {0,2,3}.
__global__ void pack_weights(const float* __restrict__ Wx1, const float* __restrict__ bx1,
                             const float* __restrict__ bconv1,
                             const float* __restrict__ Wx2, const float* __restrict__ bx2,
                             const float* __restrict__ bconv2,
                             unsigned char* __restrict__ ws) {
  const int tid = blockIdx.x * blockDim.x + threadIdx.x;
  const int stride = gridDim.x * blockDim.x;
  unsigned short* B1H = (unsigned short*)(ws + OFF_B1H);
  unsigned short* B2H = (unsigned short*)(ws + OFF_B2H);
  float* PB1 = (float*)(ws + OFF_PB1);
  float* PB2 = (float*)(ws + OFF_PB2);

  for (int idx = tid; idx < 20480; idx += stride) {
    int j = idx & 7, lane = (idx >> 3) & 63, ft = idx >> 9;  // ft = s*10+t
    int s = ft / 10, t = ft % 10;
    int k = 32 * s + ((lane >> 4) << 3) + j;
    int m = lane & 15;
    int c = -1, g = 0;
    if (t <= 8) { g = t % 3; c = 16 * (t / 3) + m; }
    else if (m < 6) { c = 48 + m / 3; g = m % 3; }
    float val = 0.f;
    if (c >= 0) {
      int gs = (g == 0) ? 0 : (g == 1) ? 2 : 3;
      val = Wx1[k * 200 + gs * 50 + c];
    }
    B1H[idx] = f2bf(val);
  }
  for (int idx = tid; idx < 4096; idx += stride) {
    int j = idx & 7, lane = (idx >> 3) & 63, ft = idx >> 9;  // ft = s*4+t
    int s = ft >> 2, t = ft & 3;
    int k = 32 * s + ((lane >> 4) << 3) + j;
    int m = lane & 15;
    int c = -1, g = 0;
    if (t <= 2) { g = t; c = m; }
    else if (m < 12) { c = 16 + m / 3; g = m % 3; }
    float val = 0.f;
    if (c >= 0 && k < 50) {
      int gs = (g == 0) ? 0 : (g == 1) ? 2 : 3;
      val = Wx2[k * 80 + gs * 20 + c];
    }
    B2H[idx] = f2bf(val);
  }
  for (int idx = tid; idx < 160; idx += stride) {
    int t = idx >> 4, m = idx & 15;
    int c = -1, g = 0;
    if (t <= 8) { g = t % 3; c = 16 * (t / 3) + m; }
    else if (m < 6) { c = 48 + m / 3; g = m % 3; }
    float v = 0.f;
    if (c >= 0) {
      int gs = (g == 0) ? 0 : (g == 1) ? 2 : 3;
      v = bx1[gs * 50 + c] + bconv1[gs * 50 + c];
    }
    PB1[idx] = v;
  }
  for (int idx = tid; idx < 64; idx += stride) {
    int t = idx >> 4, m = idx & 15;
    int c = -1, g = 0;
    if (t <= 2) { g = t; c = m; }
    else if (m < 12) { c = 16 + m / 3; g = m % 3; }
    float v = 0.f;
    if (c >= 0) {
      int gs = (g == 0) ? 0 : (g == 1) ? 2 : 3;
      v = bx2[gs * 20 + c] + bconv2[gs * 20 + c];
    }
    PB2[idx] = v;
  }
}

__global__ __launch_bounds__(256, 2) void gclstm_main(
    const float* __restrict__ x, const unsigned char* __restrict__ wsb,
    const float* __restrict__ Wl, const float* __restrict__ bl,
    float* __restrict__ out) {
  __shared__ short sB1[20480];                  // 40960 B: B1 fragments (bf16)
  __shared__ short sB2[4096];                   //  8192 B: B2 fragments (bf16)
  __shared__ unsigned short sH[4][16 * 72];     //  9216 B: per-wave h1 (bf16)
  __shared__ float sPB1[160];                   // packed-col biases L1
  __shared__ float sPB2[64];                    // packed-col biases L2

  const int tid = threadIdx.x;
  const int lane = tid & 63;
  const int wave = tid >> 6;
  const int m = lane & 15;
  const int q = lane >> 4;

  {  // stage B1/B2/biases -> LDS once; zero h scratch (K-pad cols)
    const v4f* g1 = (const v4f*)(wsb + OFF_B1H);
    v4f* s1 = (v4f*)sB1;
    for (int i = tid; i < 2560; i += 256) s1[i] = g1[i];
    const v4f* g2 = (const v4f*)(wsb + OFF_B2H);
    v4f* s2 = (v4f*)sB2;
    for (int i = tid; i < 512; i += 256) s2[i] = g2[i];
    const float* p1 = (const float*)(wsb + OFF_PB1);
    if (tid < 160) sPB1[tid] = p1[tid];
    const float* p2 = (const float*)(wsb + OFF_PB2);
    if (tid < 64) sPB2[tid] = p2[tid];
    unsigned int* hz = (unsigned int*)sH;
    for (int i = tid; i < 2304; i += 256) hz[i] = 0u;
  }
  __syncthreads();

  const float wlm = Wl[m];
  const float wlx = (m < 4) ? Wl[16 + m] : 0.f;
  const float blv = bl[0];

  unsigned short* sHw = (unsigned short*)sH + wave * (16 * 72);
  const frag8* sB1f = (const frag8*)sB1;
  const frag8* sB2f = (const frag8*)sB2;
  const int gw = blockIdx.x * 4 + wave;

  v4f abuf[8];
  int tau = gw;
  {
    const float* xr = x + (size_t)(tau * 16 + m) * 128 + q * 8;
#pragma unroll
    for (int s = 0; s < 4; ++s) {
      abuf[2 * s] = *(const v4f*)(xr + 32 * s);
      abuf[2 * s + 1] = *(const v4f*)(xr + 32 * s + 4);
    }
  }

  for (; tau < NTILES; tau += WAVES_TOTAL) {
    frag8 ah[4], al[4];
#pragma unroll
    for (int s = 0; s < 4; ++s) {
      float av[8];
      *(v4f*)av = abuf[2 * s];
      *(v4f*)(av + 4) = abuf[2 * s + 1];
      cvt8(av, ah[s], al[s]);
    }
    int tn = tau + WAVES_TOTAL;
    if (tn < NTILES) {  // prefetch next tile's x
      const float* xr = x + (size_t)(tn * 16 + m) * 128 + q * 8;
#pragma unroll
      for (int s = 0; s < 4; ++s) {
        abuf[2 * s] = *(const v4f*)(xr + 32 * s);
        abuf[2 * s + 1] = *(const v4f*)(xr + 32 * s + 4);
      }
    }

    // ---- GEMM1: z1[16 x 160] = A(hi+lo) @ B1h, bias in acc init ----
    fragC acc[10];
#pragma unroll
    for (int t = 0; t < 10; ++t) {
      float bv = sPB1[16 * t + m];
      acc[t] = (fragC){bv, bv, bv, bv};
    }
#pragma unroll
    for (int s = 0; s < 4; ++s) {
#pragma unroll
      for (int t = 0; t < 10; ++t) {
        frag8 b = sB1f[(s * 10 + t) * 64 + lane];
        acc[t] = __builtin_amdgcn_mfma_f32_16x16x32_bf16(ah[s], b, acc[t], 0, 0, 0);
        acc[t] = __builtin_amdgcn_mfma_f32_16x16x32_bf16(al[s], b, acc[t], 0, 0, 0);
      }
      // cap B-frag hoisting to one k-stage (10 frags = 40 VGPRs): the R4/R5
      // spill storm was the scheduler lifting all 40 frags (160 VGPRs).
      __builtin_amdgcn_sched_barrier(0);
    }

    // gates from registers (packed-col): lane (m,q) -> rows 4q+r, channel 16b+m
#pragma unroll
    for (int b = 0; b < 3; ++b)
#pragma unroll
      for (int r = 0; r < 4; ++r) {
        float I = fsig(acc[3 * b][r]);
        float T = ftanh(acc[3 * b + 1][r]);
        float O = fsig(acc[3 * b + 2][r]);
        sHw[(q * 4 + r) * 72 + 16 * b + m] = f2bf(O * ftanh(I * T));
      }
    // channels 48,49 from acc[9] via shfl: c48 lanes 16q+{0,1,2}, c49 +{3,4,5}
#pragma unroll
    for (int r = 0; r < 4; ++r) {
      float vI = __shfl(acc[9][r], 16 * q + m);
      float vT = __shfl(acc[9][r], 16 * q + m + 1);
      float vO = __shfl(acc[9][r], 16 * q + m + 2);
      if (m == 0 || m == 3) {
        float I = fsig(vI), T = ftanh(vT), O = fsig(vO);
        sHw[(q * 4 + r) * 72 + 48 + (m >> 1)] = f2bf(O * ftanh(I * T));
      }
    }

    // ---- GEMM2: z2[16 x 64] = h1(bf16) @ B2h, K padded to 64 ----
    frag8 hh[2];
#pragma unroll
    for (int s = 0; s < 2; ++s)
      hh[s] = *(const frag8*)(sHw + m * 72 + 32 * s + 8 * q);
    fragC acc2[4];
#pragma unroll
    for (int t = 0; t < 4; ++t) {
      float bv = sPB2[16 * t + m];
      acc2[t] = (fragC){bv, bv, bv, bv};
    }
#pragma unroll
    for (int s = 0; s < 2; ++s)
#pragma unroll
      for (int t = 0; t < 4; ++t) {
        frag8 b = sB2f[(s * 4 + t) * 64 + lane];
        acc2[t] = __builtin_amdgcn_mfma_f32_16x16x32_bf16(hh[s], b, acc2[t], 0, 0, 0);
      }

    // epilogue in registers: lane owns ch m (t=0,1,2) and (m<4) ch 16+m via shfl
    v4f res;
#pragma unroll
    for (int r = 0; r < 4; ++r) {
      float I = fsig(acc2[0][r]);
      float T = ftanh(acc2[1][r]);
      float O = fsig(acc2[2][r]);
      float h2 = O * ftanh(I * T);
      float part = fmaxf(h2, 0.f) * wlm;
      float eI = __shfl(acc2[3][r], 16 * q + 3 * m);
      float eT = __shfl(acc2[3][r], 16 * q + 3 * m + 1);
      float eO = __shfl(acc2[3][r], 16 * q + 3 * m + 2);
      float I2 = fsig(eI), T2 = ftanh(eT), O2 = fsig(eO);
      float h2x = O2 * ftanh(I2 * T2);
      part += fmaxf(h2x, 0.f) * wlx;
      part += __shfl_xor(part, 1);
      part += __shfl_xor(part, 2);
      part += __shfl_xor(part, 4);
      part += __shfl_xor(part, 8);
      res[r] = part + blv;
    }
    if (m == 0) *(v4f*)(out + tau * 16 + 4 * q) = res;
  }
}

extern "C" void kernel_launch(void* const* d_in, const int* in_sizes, int n_in,
                              void* d_out, int out_size, void* d_ws, size_t ws_size,
                              hipStream_t stream) {
  (void)in_sizes; (void)n_in; (void)out_size; (void)ws_size;
  const float* x = (const float*)d_in[0];
  // d_in[1] edge_index, d_in[2] edge_weight, d_in[5] theta1, d_in[9] theta2: dead
  const float* Wx1 = (const float*)d_in[3];
  const float* bx1 = (const float*)d_in[4];
  const float* bconv1 = (const float*)d_in[6];
  const float* Wx2 = (const float*)d_in[7];
  const float* bx2 = (const float*)d_in[8];
  const float* bconv2 = (const float*)d_in[10];
  const float* Wl = (const float*)d_in[11];
  const float* bl = (const float*)d_in[12];
  unsigned char* ws = (unsigned char*)d_ws;  // needs ~50 KB

  hipLaunchKernelGGL(pack_weights, dim3(32), dim3(256), 0, stream,
                     Wx1, bx1, bconv1, Wx2, bx2, bconv2, ws);
  hipLaunchKernelGGL(gclstm_main, dim3(GRID_BLOCKS), dim3(256), 0, stream,
                     x, ws, Wl, bl, (float*)d_out);
}